// Round 7
// baseline (90.236 us; speedup 1.0000x reference)
//
#include <hip/hip_runtime.h>
#include <hip/hip_bf16.h>

typedef __attribute__((ext_vector_type(8))) __bf16 bf16x8;
typedef __attribute__((ext_vector_type(4))) float f32x4;

static constexpr int BROWS = 65536;
static constexpr int SDIM  = 512;
static constexpr int CDIM  = 256;
static constexpr float SLOPE = 0.01f;
static constexpr float HLP = 0.9189385332046727f;  // 0.5*log(2*pi)

// ws bf16 layout: W1T [64][512], W2T [32][64], W3T [256][32]
static constexpr int W1T_OFF = 0;
static constexpr int W2T_OFF = 64 * 512;
static constexpr int W3T_OFF = 64 * 512 + 32 * 64;
static constexpr int WS_ELEMS = W3T_OFF + 256 * 32;   // 43008

__global__ __launch_bounds__(256) void prep_weights(
    const float* __restrict__ W1, const float* __restrict__ W2,
    const float* __restrict__ W3, __bf16* __restrict__ ws)
{
    int tid = blockIdx.x * 256 + threadIdx.x;
    if (tid < 64 * 512) {                       // W1 [512][64] -> W1T [64][512]
        int n = tid >> 9, k = tid & 511;
        ws[W1T_OFF + tid] = (__bf16)W1[k * 64 + n];
    } else if (tid < 64 * 512 + 32 * 64) {      // W2 [64][32] -> W2T [32][64]
        int t = tid - 64 * 512;
        int n = t >> 6, k = t & 63;
        ws[W2T_OFF + t] = (__bf16)W2[k * 32 + n];
    } else if (tid < WS_ELEMS) {                // W3 [32][256] -> W3T [256][32]
        int t = tid - (64 * 512 + 32 * 64);
        int n = t >> 5, k = t & 31;
        ws[W3T_OFF + t] = (__bf16)W3[k * 256 + n];
    }
}

// swizzled LDS element index for bf16 [16][64] tiles: row stride 128B
__device__ __forceinline__ int swz(int row, int elem) {
    return (row * 64 + elem) ^ ((row & 7) << 3);
}

__device__ __forceinline__ bf16x8 cvt8(f32x4 a, f32x4 b) {
    bf16x8 r = {(__bf16)a.x, (__bf16)a.y, (__bf16)a.z, (__bf16)a.w,
                (__bf16)b.x, (__bf16)b.y, (__bf16)b.z, (__bf16)b.w};
    return r;
}

// One wave (64 thr) per block, 16 rows per block, 4096 blocks.
// state tile DMA'd to LDS via global_load_lds (async, no VGPR, cannot be sunk);
// noise batched into 64 VGPRs and pinned before a single vmcnt(0) fence, so all
// ~48 global requests are in flight at once and read latency is paid ONCE.
// LDS 32 KB: state [16 rows][2048 B] with 16B-chunk XOR swizzle (^(row&7)<<4),
// achieved by pre-swizzling the DMA *source* address (LDS dest must be linear).
// After layer 1 the state buffer is dead; h1/h2/mt reuse its first 8.5 KB.
__global__ __launch_bounds__(64, 2) void policy_fused(
    const float* __restrict__ state, const float* __restrict__ b1,
    const float* __restrict__ b2, const float* __restrict__ b3,
    const float* __restrict__ noise, const __bf16* __restrict__ ws,
    float* __restrict__ actions, float* __restrict__ logp)
{
    __shared__ __align__(64) char lds[32768];

    const int lane = threadIdx.x & 63;
    const int lr   = lane & 15;   // A-row / B-col index
    const int lq   = lane >> 4;   // k-chunk / C-row-quad index
    const int rowbase = blockIdx.x * 16;

    const __bf16* W1T = ws + W1T_OFF;
    const __bf16* W2T = ws + W2T_OFF;
    const __bf16* W3T = ws + W3T_OFF;

    // ---- async DMA: state [16][512] f32 -> LDS, source pre-swizzled ----
    #pragma unroll
    for (int j = 0; j < 32; ++j) {
        const int row = j >> 1;
        const unsigned bofs  = (unsigned)((j & 1) * 1024 + lane * 16);
        const unsigned sbyte = bofs ^ (unsigned)((row & 7) << 4);
        const float* src = state + (size_t)(rowbase + row) * SDIM + (sbyte >> 2);
        __builtin_amdgcn_global_load_lds(
            (const __attribute__((address_space(1))) void*)src,
            (__attribute__((address_space(3))) void*)(lds + row * 2048 + (j & 1) * 1024),
            16, 0, 0);
    }

    // ---- batched noise loads into VGPRs (pinned: cannot sink past the fence) ----
    const int erow = lane >> 2;          // epilogue row 0..15
    const int q    = lane & 3;           // 16-col quarter
    const size_t gb = (size_t)(rowbase + erow) * CDIM;
    f32x4 nv[4][4];
    #pragma unroll
    for (int g = 0; g < 4; ++g)
        #pragma unroll
        for (int j = 0; j < 4; ++j)
            nv[g][j] = *(const f32x4*)(noise + gb + g * 64 + q * 16 + j * 4);

    asm volatile("s_waitcnt vmcnt(0)" ::: "memory");
    __builtin_amdgcn_sched_barrier(0);

    const f32x4 zero4 = {0.f, 0.f, 0.f, 0.f};

    // ---------------- layer 1: 16 rows x 64 cols, K=512 from LDS ----------------
    f32x4 acc[4] = {zero4, zero4, zero4, zero4};
    const int rowb = lr * 2048;
    const unsigned xs = (unsigned)((lr & 7) << 4);
    #pragma unroll
    for (int s = 0; s < 16; ++s) {
        const unsigned c0 = (unsigned)(s * 128 + lq * 32);
        f32x4 a0 = *(const f32x4*)(lds + rowb + (c0 ^ xs));
        f32x4 a1 = *(const f32x4*)(lds + rowb + ((c0 + 16) ^ xs));
        bf16x8 a = cvt8(a0, a1);
        #pragma unroll
        for (int n = 0; n < 4; ++n) {
            bf16x8 b = *(const bf16x8*)(W1T + (n * 16 + lr) * SDIM + s * 32 + lq * 8);
            acc[n] = __builtin_amdgcn_mfma_f32_16x16x32_bf16(a, b, acc[n], 0, 0, 0);
        }
    }

    // state buffer dead from here; reuse for h1 / h2 / mean-transpose
    __bf16* h1 = (__bf16*)lds;             // [16][64] bf16 swz, 2 KB
    __bf16* h2 = (__bf16*)(lds + 2048);    // [16][64] bf16 swz, 2 KB
    float*  mt = (float*)(lds + 4096);     // [16][68] f32, 4352 B

    #pragma unroll
    for (int n = 0; n < 4; ++n) {
        float bv = b1[n * 16 + lr];
        #pragma unroll
        for (int r = 0; r < 4; ++r) {
            float v = acc[n][r] + bv;
            v = (v >= 0.f) ? v : SLOPE * v;
            h1[swz(lq * 4 + r, n * 16 + lr)] = (__bf16)v;
        }
    }

    // ---------------- layer 2: 16 rows x 32 cols, K=64 ----------------
    f32x4 c2[2] = {zero4, zero4};
    #pragma unroll
    for (int kk = 0; kk < 2; ++kk) {
        bf16x8 a = *(const bf16x8*)&h1[swz(lr, kk * 32 + lq * 8)];
        #pragma unroll
        for (int n = 0; n < 2; ++n) {
            bf16x8 b = *(const bf16x8*)(W2T + (n * 16 + lr) * 64 + kk * 32 + lq * 8);
            c2[n] = __builtin_amdgcn_mfma_f32_16x16x32_bf16(a, b, c2[n], 0, 0, 0);
        }
    }
    #pragma unroll
    for (int n = 0; n < 2; ++n) {
        float bv = b2[n * 16 + lr];
        #pragma unroll
        for (int r = 0; r < 4; ++r) {
            float v = c2[n][r] + bv;
            v = (v >= 0.f) ? v : SLOPE * v;
            h2[swz(lq * 4 + r, n * 16 + lr)] = (__bf16)v;
        }
    }
    bf16x8 a3 = *(const bf16x8*)&h2[swz(lr, lq * 8)];

    // ---------------- layer 3 + epilogue, 4 groups of 64 cols ----------------
    float lp = 0.f;
    #pragma unroll
    for (int g = 0; g < 4; ++g) {
        #pragma unroll
        for (int t = 0; t < 4; ++t) {
            bf16x8 bf = *(const bf16x8*)(W3T + (g * 64 + t * 16 + lr) * 32 + lq * 8);
            f32x4 c = __builtin_amdgcn_mfma_f32_16x16x32_bf16(a3, bf, zero4, 0, 0, 0);
            #pragma unroll
            for (int r = 0; r < 4; ++r)
                mt[(lq * 4 + r) * 68 + t * 16 + lr] = c[r];
        }
        #pragma unroll
        for (int j = 0; j < 4; ++j) {
            f32x4 m4 = *(const f32x4*)&mt[erow * 68 + q * 16 + j * 4];
            f32x4 bb = *(const f32x4*)(b3 + g * 64 + q * 16 + j * 4);
            f32x4 mean = m4 + bb;
            f32x4 av = mean + nv[g][j];
            *(f32x4*)(actions + gb + g * 64 + q * 16 + j * 4) = av;
            f32x4 zv = av - mean;          // replicate reference rounding exactly
            lp += -0.5f * (zv.x * zv.x + zv.y * zv.y + zv.z * zv.z + zv.w * zv.w) - 4.0f * HLP;
        }
    }
    // 4 lanes (q) share each row
    lp += __shfl_xor(lp, 1, 64);
    lp += __shfl_xor(lp, 2, 64);
    if (q == 0)
        logp[rowbase + erow] = lp;
}

extern "C" void kernel_launch(void* const* d_in, const int* in_sizes, int n_in,
                              void* d_out, int out_size, void* d_ws, size_t ws_size,
                              hipStream_t stream)
{
    const float* state = (const float*)d_in[0];
    const float* W1    = (const float*)d_in[1];
    const float* b1    = (const float*)d_in[2];
    const float* W2    = (const float*)d_in[3];
    const float* b2    = (const float*)d_in[4];
    const float* W3    = (const float*)d_in[5];
    const float* b3    = (const float*)d_in[6];
    const float* noise = (const float*)d_in[7];

    if (ws_size < (size_t)WS_ELEMS * sizeof(__bf16)) return;  // need 86 KB scratch
    __bf16* ws = (__bf16*)d_ws;

    float* actions = (float*)d_out;
    float* logp    = actions + (size_t)BROWS * CDIM;

    prep_weights<<<(WS_ELEMS + 255) / 256, 256, 0, stream>>>(W1, W2, W3, ws);
    policy_fused<<<BROWS / 16, 64, 0, stream>>>(state, b1, b2, b3, noise, ws,
                                                actions, logp);
}

// Round 8
// 69.061 us; speedup vs baseline: 1.3066x; 1.3066x over previous
//
#include <hip/hip_runtime.h>
#include <hip/hip_bf16.h>

typedef __attribute__((ext_vector_type(8))) __bf16 bf16x8;
typedef __attribute__((ext_vector_type(4))) float f32x4;

static constexpr int BROWS = 65536;
static constexpr int SDIM  = 512;
static constexpr int CDIM  = 256;
static constexpr float SLOPE = 0.01f;
static constexpr float HLP = 0.9189385332046727f;  // 0.5*log(2*pi)

// ws bf16 layout: W1T [64][512], W2T [32][64], W3T [256][32]
static constexpr int W1T_OFF = 0;
static constexpr int W2T_OFF = 64 * 512;
static constexpr int W3T_OFF = 64 * 512 + 32 * 64;
static constexpr int WS_ELEMS = W3T_OFF + 256 * 32;   // 43008

__global__ __launch_bounds__(256) void prep_weights(
    const float* __restrict__ W1, const float* __restrict__ W2,
    const float* __restrict__ W3, __bf16* __restrict__ ws)
{
    int tid = blockIdx.x * 256 + threadIdx.x;
    if (tid < 64 * 512) {                       // W1 [512][64] -> W1T [64][512]
        int n = tid >> 9, k = tid & 511;
        ws[W1T_OFF + tid] = (__bf16)W1[k * 64 + n];
    } else if (tid < 64 * 512 + 32 * 64) {      // W2 [64][32] -> W2T [32][64]
        int t = tid - 64 * 512;
        int n = t >> 6, k = t & 63;
        ws[W2T_OFF + t] = (__bf16)W2[k * 32 + n];
    } else if (tid < WS_ELEMS) {                // W3 [32][256] -> W3T [256][32]
        int t = tid - (64 * 512 + 32 * 64);
        int n = t >> 5, k = t & 31;
        ws[W3T_OFF + t] = (__bf16)W3[k * 256 + n];
    }
}

// swizzled LDS element index: row stride 64 bf16 (128B), XOR row&7 into 16B-chunk bits
__device__ __forceinline__ int swz(int row, int elem) {
    return (row * 64 + elem) ^ ((row & 7) << 3);
}

__device__ __forceinline__ bf16x8 cvt8(f32x4 a, f32x4 b) {
    bf16x8 r = {(__bf16)a.x, (__bf16)a.y, (__bf16)a.z, (__bf16)a.w,
                (__bf16)b.x, (__bf16)b.y, (__bf16)b.z, (__bf16)b.w};
    return r;
}

// mean-transpose LDS tile: per-wave 16 rows x 68-float stride (272 B rows, 16B-aligned)
static constexpr int MT_STRIDE = 68;

__global__ __launch_bounds__(256, 4) void policy_fused(
    const float* __restrict__ state, const float* __restrict__ b1,
    const float* __restrict__ b2, const float* __restrict__ b3,
    const float* __restrict__ noise, const __bf16* __restrict__ ws,
    float* __restrict__ actions, float* __restrict__ logp)
{
    __shared__ __align__(16) __bf16 h1s[64 * 64];          // 8 KB (per-wave 16-row stripes)
    __shared__ __align__(16) __bf16 h2s[64 * 64];          // 8 KB
    __shared__ __align__(16) float  mtile[4][16 * MT_STRIDE]; // 17 KB, per-wave buffer

    const int tid  = threadIdx.x;
    const int wave = tid >> 6;
    const int lane = tid & 63;
    const int lr   = lane & 15;   // A-row / B-col index
    const int lq   = lane >> 4;   // k-chunk / C-row-quad index

    const int rowbase = blockIdx.x * 64 + wave * 16;   // this wave's 16 rows

    const __bf16* W1T = ws + W1T_OFF;
    const __bf16* W2T = ws + W2T_OFF;
    const __bf16* W3T = ws + W3T_OFF;

    const f32x4 zero4 = {0.f, 0.f, 0.f, 0.f};

    // preload tiny biases (L1/L2-hot)
    float bv1[4], bv2[2];
    #pragma unroll
    for (int n = 0; n < 4; ++n) bv1[n] = b1[n * 16 + lr];
    #pragma unroll
    for (int n = 0; n < 2; ++n) bv2[n] = b2[n * 16 + lr];

    // ---------------- layer 1: [16 rows] x [64 cols], K=512 ----------------
    f32x4 acc[4] = {zero4, zero4, zero4, zero4};
    const float* sp = state + (size_t)(rowbase + lr) * SDIM + lq * 8;
    const __bf16* wbase = W1T + lr * SDIM + lq * 8;
    #pragma unroll 4
    for (int k0 = 0; k0 < SDIM; k0 += 32) {
        f32x4 sa = *(const f32x4*)(sp + k0);
        f32x4 sb = *(const f32x4*)(sp + k0 + 4);
        bf16x8 a = cvt8(sa, sb);
        #pragma unroll
        for (int n = 0; n < 4; ++n) {
            bf16x8 b = *(const bf16x8*)(wbase + k0 + n * 16 * SDIM);
            acc[n] = __builtin_amdgcn_mfma_f32_16x16x32_bf16(a, b, acc[n], 0, 0, 0);
        }
    }
    #pragma unroll
    for (int n = 0; n < 4; ++n) {
        #pragma unroll
        for (int r = 0; r < 4; ++r) {
            float v = acc[n][r] + bv1[n];
            v = (v >= 0.f) ? v : SLOPE * v;
            int row = wave * 16 + lq * 4 + r;
            h1s[swz(row, n * 16 + lr)] = (__bf16)v;
        }
    }
    // no __syncthreads(): each wave touches only its own 16-row stripe (in-order DS)

    // ---------------- layer 2: [16 rows] x [32 cols], K=64 ----------------
    f32x4 c2[2] = {zero4, zero4};
    #pragma unroll
    for (int kk = 0; kk < 2; ++kk) {
        bf16x8 a = *(const bf16x8*)&h1s[swz(wave * 16 + lr, kk * 32 + lq * 8)];
        #pragma unroll
        for (int n = 0; n < 2; ++n) {
            bf16x8 b = *(const bf16x8*)(W2T + (n * 16 + lr) * 64 + kk * 32 + lq * 8);
            c2[n] = __builtin_amdgcn_mfma_f32_16x16x32_bf16(a, b, c2[n], 0, 0, 0);
        }
    }
    #pragma unroll
    for (int n = 0; n < 2; ++n) {
        #pragma unroll
        for (int r = 0; r < 4; ++r) {
            float v = c2[n][r] + bv2[n];
            v = (v >= 0.f) ? v : SLOPE * v;
            int row = wave * 16 + lq * 4 + r;
            h2s[swz(row, n * 16 + lr)] = (__bf16)v;
        }
    }

    // ---------------- layer 3 + epilogue, 4 groups of 64 cols ----------------
    // Read-back column mapping: col = j*16 + q*4, so each 4-lane row-group (q=0..3)
    // covers one CONTIGUOUS 64-B line per store instruction -> full-line nontemporal
    // stores (no partial-line HBM amplification), and no L3 allocation for actions.
    bf16x8 a3 = *(const bf16x8*)&h2s[swz(wave * 16 + lr, lq * 8)];
    float* mt = &mtile[wave][0];
    const int row = lane >> 2;            // 0..15 (read-back row)
    const int q   = lane & 3;             // 16-B sub-chunk within the 64-B line
    const size_t gbase = (size_t)(rowbase + row) * CDIM;
    float lp = 0.f;

    f32x4 nbuf[2][4];
    bf16x8 w3f[2][4];
    #pragma unroll
    for (int j = 0; j < 4; ++j) {
        nbuf[0][j] = *(const f32x4*)(noise + gbase + j * 16 + q * 4);
        w3f[0][j]  = *(const bf16x8*)(W3T + (j * 16 + lr) * 32 + lq * 8);
    }

    #pragma unroll
    for (int g = 0; g < 4; ++g) {
        // prefetch next group's noise + W3T frags
        if (g < 3) {
            #pragma unroll
            for (int j = 0; j < 4; ++j) {
                nbuf[(g + 1) & 1][j] = *(const f32x4*)(noise + gbase + (g + 1) * 64 + j * 16 + q * 4);
                w3f[(g + 1) & 1][j]  = *(const bf16x8*)(W3T + ((g + 1) * 64 + j * 16 + lr) * 32 + lq * 8);
            }
        }
        f32x4 b3v[4];
        #pragma unroll
        for (int j = 0; j < 4; ++j)
            b3v[j] = *(const f32x4*)(b3 + g * 64 + j * 16 + q * 4);

        // MFMA phase: 4 col-tiles -> per-wave LDS transpose buffer
        #pragma unroll
        for (int t = 0; t < 4; ++t) {
            f32x4 c = __builtin_amdgcn_mfma_f32_16x16x32_bf16(a3, w3f[g & 1][t], zero4, 0, 0, 0);
            #pragma unroll
            for (int r = 0; r < 4; ++r)
                mt[(lq * 4 + r) * MT_STRIDE + t * 16 + lr] = c[r];
        }
        // read-back phase: vectorized, contiguous per 4-lane group
        #pragma unroll
        for (int j = 0; j < 4; ++j) {
            f32x4 m4 = *(const f32x4*)&mt[row * MT_STRIDE + j * 16 + q * 4];
            f32x4 mean = m4 + b3v[j];
            f32x4 av = mean + nbuf[g & 1][j];
            __builtin_nontemporal_store(av, (f32x4*)(actions + gbase + g * 64 + j * 16 + q * 4));
            f32x4 zv = av - mean;          // replicate reference rounding exactly
            lp += -0.5f * (zv.x * zv.x + zv.y * zv.y + zv.z * zv.z + zv.w * zv.w) - 4.0f * HLP;
        }
    }
    // 4 lanes (q=0..3) share each row
    lp += __shfl_xor(lp, 1, 64);
    lp += __shfl_xor(lp, 2, 64);
    if (q == 0)
        logp[rowbase + row] = lp;
}

extern "C" void kernel_launch(void* const* d_in, const int* in_sizes, int n_in,
                              void* d_out, int out_size, void* d_ws, size_t ws_size,
                              hipStream_t stream)
{
    const float* state = (const float*)d_in[0];
    const float* W1    = (const float*)d_in[1];
    const float* b1    = (const float*)d_in[2];
    const float* W2    = (const float*)d_in[3];
    const float* b2    = (const float*)d_in[4];
    const float* W3    = (const float*)d_in[5];
    const float* b3    = (const float*)d_in[6];
    const float* noise = (const float*)d_in[7];

    if (ws_size < (size_t)WS_ELEMS * sizeof(__bf16)) return;  // need 86 KB scratch
    __bf16* ws = (__bf16*)d_ws;

    float* actions = (float*)d_out;
    float* logp    = actions + (size_t)BROWS * CDIM;

    prep_weights<<<(WS_ELEMS + 255) / 256, 256, 0, stream>>>(W1, W2, W3, ws);
    policy_fused<<<BROWS / 64, 256, 0, stream>>>(state, b1, b2, b3, noise, ws,
                                                 actions, logp);
}